// Round 12
// baseline (194.836 us; speedup 1.0000x reference)
//
#include <hip/hip_runtime.h>
#include <hip/hip_bf16.h>

#define Bb 4
#define Tt 1024
#define Ee 768
#define Hh 12
#define Dd 64
#define NTOK (Bb*Tt)   // 4096

// softmax scale 1/sqrt(D)/TEMP folded with log2(e) into Wq/bq so the
// exponential is a bare v_exp_f32 (2^x) on the raw MFMA output.
#define QSCALE 0.18033688f   // 0.125 * log2(e)

typedef __attribute__((ext_vector_type(8))) short bf16x8;  // 8 bf16 in 4 VGPRs
typedef __attribute__((ext_vector_type(4))) float f32x4;   // MFMA accumulator

__device__ __forceinline__ f32x4 mfma16(bf16x8 a, bf16x8 b, f32x4 c) {
  return __builtin_amdgcn_mfma_f32_16x16x32_bf16(a, b, c, 0, 0, 0);
}
__device__ __forceinline__ float exp2x(float x) {
  return __builtin_amdgcn_exp2f(x);
}

// fp32 -> bf16 round-to-nearest-even
__device__ __forceinline__ ushort f2b(float f) {
  uint u = __builtin_bit_cast(uint, f);
  return (ushort)((u + 0x7fffu + ((u >> 16) & 1u)) >> 16);
}
__device__ __forceinline__ uint pack2(float a, float b) {
  return (uint)f2b(a) | ((uint)f2b(b) << 16);
}

// async global->LDS, 16B per lane. LDS dest is wave-uniform base + lane*16.
typedef const __attribute__((address_space(1))) void GV;
typedef __attribute__((address_space(3))) void LV;
__device__ __forceinline__ void gload16(const void* g, void* l) {
  __builtin_amdgcn_global_load_lds((GV*)g, (LV*)l, 16, 0, 0);
}

// ---------------- convert: fp32 -> bf16 (* scale), 8 elems/thread --------
struct CvtSeg { const float* src; ushort* dst; int n8; float scale; };
struct CvtArgs { CvtSeg seg[11]; };

__global__ __launch_bounds__(256) void convert_kernel(CvtArgs a) {
  const CvtSeg s = a.seg[blockIdx.y];
  const int i = blockIdx.x * 256 + threadIdx.x;
  if (i >= s.n8) return;
  const float4 v0 = ((const float4*)s.src)[2*i];
  const float4 v1 = ((const float4*)s.src)[2*i + 1];
  uint4 o;
  o.x = pack2(v0.x * s.scale, v0.y * s.scale);
  o.y = pack2(v0.z * s.scale, v0.w * s.scale);
  o.z = pack2(v1.x * s.scale, v1.y * s.scale);
  o.w = pack2(v1.z * s.scale, v1.w * s.scale);
  ((uint4*)s.dst)[i] = o;
}

// ---------------- bf16 GEMM: C[M,N] = A[M,K] @ W[N,K]^T + bias*bscale ----
// 128x128 tile, BK=64, 4 waves (each a 64x64 quadrant, 4x4 frags).
// Double-buffered LDS with prefetch-before-compute ((256,2): 256-reg cap,
// no spill risk). XOR-swizzle staging (pre-swizzled source + swizzled
// ds_read; involution byte^=(row&7)<<4).
template<bool OUT_BF16>
__device__ __forceinline__ void gemm_bf16(
    const ushort* __restrict__ A, const ushort* __restrict__ Bw,
    const float* __restrict__ bias, const float bscale, void* __restrict__ Cp,
    const int K, const int N)
{
  __shared__ ushort Ash[2][128][64];
  __shared__ ushort Bsh[2][128][64];
  const int tid  = threadIdx.x;
  const int lane = tid & 63;
  const int wave = tid >> 6;
  const int m0 = blockIdx.x * 128;
  const int n0 = blockIdx.y * 128;
  const int wm = (wave >> 1) << 6;
  const int wn = (wave & 1) << 6;
  const int srow = lane >> 3;                       // 0..7 within 8-row group
  const int scol = ((lane & 7) ^ srow) << 3;        // swizzled element offset
  const ushort* Ag = A  + (size_t)(m0 + wave*8 + srow) * K + scol;
  const ushort* Bg = Bw + (size_t)(n0 + wave*8 + srow) * K + scol;

  auto stage = [&](int buf, int k0) {
#pragma unroll
    for (int rr = 0; rr < 4; rr++) {
      gload16(Ag + (size_t)(rr*32) * K + k0, &Ash[buf][rr*32 + wave*8][0]);
      gload16(Bg + (size_t)(rr*32) * K + k0, &Bsh[buf][rr*32 + wave*8][0]);
    }
  };

  stage(0, 0);
  asm volatile("s_waitcnt vmcnt(0)" ::: "memory");
  __syncthreads();

  const int nk = K / 64;
  f32x4 acc[4][4] = {};
  for (int kt = 0; kt < nk; kt++) {
    const int cur = kt & 1;
    if (kt + 1 < nk) stage(cur ^ 1, (kt + 1) * 64);
#pragma unroll
    for (int kk = 0; kk < 2; kk++) {
      const int pcb = (((lane >> 4) << 4) + kk*64) ^ ((lane & 7) << 4);
      bf16x8 af[4], bfv[4];
#pragma unroll
      for (int m = 0; m < 4; m++)
        af[m] = *(const bf16x8*)((const char*)&Ash[cur][wm + m*16 + (lane & 15)][0] + pcb);
#pragma unroll
      for (int n = 0; n < 4; n++)
        bfv[n] = *(const bf16x8*)((const char*)&Bsh[cur][wn + n*16 + (lane & 15)][0] + pcb);
#pragma unroll
      for (int m = 0; m < 4; m++)
#pragma unroll
        for (int n = 0; n < 4; n++)
          acc[m][n] = mfma16(af[m], bfv[n], acc[m][n]);
    }
    __syncthreads();   // drains vmcnt (prefetch) + lgkmcnt, seals buffers
  }
  // C/D layout: col = lane&15, row = (lane>>4)*4 + reg  [m89-verified]
#pragma unroll
  for (int n = 0; n < 4; n++) {
    const int col = n0 + wn + n*16 + (lane & 15);
    const float bv = bias[col] * bscale;
#pragma unroll
    for (int m = 0; m < 4; m++) {
#pragma unroll
      for (int r = 0; r < 4; r++) {
        const int row = m0 + wm + m*16 + ((lane >> 4) << 2) + r;
        const float v = acc[m][n][r] + bv;
        if (OUT_BF16) ((ushort*)Cp)[(size_t)row * N + col] = f2b(v);
        else          ((float*)Cp)[(size_t)row * N + col] = v;
      }
    }
  }
}

struct ProjPtrs {
  const ushort* X[5];
  const ushort* W[5];
  const float* b[5];
  float bscale[5];
  ushort* out[5];
};

__global__ __launch_bounds__(256, 2) void proj5_kernel(ProjPtrs p) {
  const int z = blockIdx.z;
  gemm_bf16<true>(p.X[z], p.W[z], p.b[z], p.bscale[z], p.out[z], Ee, Ee);
}

__global__ __launch_bounds__(256, 2) void outproj_kernel(
    const ushort* __restrict__ A, const ushort* __restrict__ W,
    const float* __restrict__ bias, float* __restrict__ C) {
  gemm_bf16<false>(A, W, bias, 1.0f, C, Ee, Ee);
}

// ---------------- Attention ----------------
// Global-flat softmax: a_j = 2^(St_j)/Z_j * T, Z_j = sum over all (t,s) per
// (b,h). Scores bounded so raw exp2 in fp32 is safe (Q pre-scaled by QSCALE).
//
// CODEGEN LESSONS:
// (r5-r9) statically-known s-loop trip count <= 8 gets FULLY UNROLLED and
// the merged live ranges spill ~1.3 KB/thread (500+ MB/launch, 5-6x). Pin
// with #pragma unroll 1 — this made dbuf safe (r11: 52 VGPR, no spill).
// (r10) z-split at (256,4) regressed: 1536 blocks on 1024 slots = 1.5
// dispatch rounds (tail). Exact-fit rule: resident slots must equal grid.
// (r12) z-split + (256,6): 1536 blocks = 1536 slots = 1 round, 6 w/SIMD.

// pass1: Z[bh*3+j] = sum 2^s_j. grid (48 bh, 16 strips, 2 s-halves),
// 4 waves x 16 rows, 8 K-tiles per block, dbuf, rolled.
__global__ __launch_bounds__(256, 6) void attn_pass1(
    const ushort* __restrict__ q1, const ushort* __restrict__ q2,
    const ushort* __restrict__ q3, const ushort* __restrict__ kmat,
    float* __restrict__ Z)
{
  const int bh = blockIdx.x;
  const int b = bh / Hh, h = bh % Hh;
  const int lane = threadIdx.x & 63;
  const int wave = threadIdx.x >> 6;
  const int trow0 = blockIdx.y * 64 + wave * 16;

  __shared__ ushort Ksh[2][64][64];   // dbuf; XOR-swizzled content

  const int srow = lane >> 3;
  const int scolb = ((lane & 7) ^ srow) << 4;       // byte offset in 128B row
  // z-offset folded into base pointer; loop bounds compile-time.
  const ushort* Kg = kmat + ((size_t)(b*Tt) + blockIdx.z*(Tt/2))*Ee + h*Dd;

  auto stageK = [&](int buf, int s0) {
#pragma unroll
    for (int rr = 0; rr < 2; rr++) {
      const int rowbase = rr*32 + wave*8;
      gload16((const char*)(Kg + (size_t)(s0 + rowbase + srow)*Ee) + scolb,
              &Ksh[buf][rowbase][0]);
    }
  };

  const ushort* qs[3] = {q1, q2, q3};
  bf16x8 qf[3][2];
#pragma unroll
  for (int j = 0; j < 3; j++)
#pragma unroll
    for (int kk = 0; kk < 2; kk++) {
      const int t = trow0 + (lane & 15);
      const int d = kk*32 + ((lane >> 4) << 3);
      qf[j][kk] = *(const bf16x8*)(qs[j] + ((size_t)(b*Tt + t))*Ee + h*Dd + d);
    }

  stageK(0, 0);
  asm volatile("s_waitcnt vmcnt(0)" ::: "memory");
  __syncthreads();

  float zacc[3] = {0.f, 0.f, 0.f};
#pragma unroll 1   // MUST stay rolled (spill lesson r5-r10)
  for (int it = 0; it < 8; it++) {
    const int cur = it & 1;
    if (it + 1 < 8) stageK(cur ^ 1, (it + 1) * 64);   // overlaps compute
    bf16x8 kf[4][2];
#pragma unroll
    for (int n = 0; n < 4; n++)
#pragma unroll
      for (int kk = 0; kk < 2; kk++)
        kf[n][kk] = *(const bf16x8*)((const char*)&Ksh[cur][n*16 + (lane & 15)][0] +
                      ((((lane >> 4) << 4) + kk*64) ^ ((lane & 7) << 4)));
#pragma unroll
    for (int j = 0; j < 3; j++) {
      f32x4 sacc[4] = {};
#pragma unroll
      for (int kk = 0; kk < 2; kk++)
#pragma unroll
        for (int n = 0; n < 4; n++)
          sacc[n] = mfma16(qf[j][kk], kf[n][kk], sacc[n]);
      float s = 0.f;
#pragma unroll
      for (int n = 0; n < 4; n++)
#pragma unroll
        for (int r = 0; r < 4; r++)
          s += exp2x(sacc[n][r]);
      zacc[j] += s;
    }
    __syncthreads();   // one barrier/iter: seals prefetch, releases cur
  }
#pragma unroll
  for (int j = 0; j < 3; j++) {
    float v = zacc[j];
#pragma unroll
    for (int off = 32; off > 0; off >>= 1) v += __shfl_xor(v, off, 64);
    if (lane == 0) atomicAdd(&Z[bh*3 + j], v);
  }
}

// pass2: O[t,d] = sum_s P[t,s] V[s,d], P = sum_j c_j 2^s_j, c_j = T/(3 Z_j).
// Swapped QK (S^T = mfma(K,Q)): lane's 4 C-regs are 4 consecutive s for one
// t -> P write is 4x b64. Double-buffered K (gload_lds) and V (reg-stage,
// T14 issue-early/write-late); Psh single (own-wave rows, in-iter reuse).
__global__ __launch_bounds__(256, 3) void attn_pass2(
    const ushort* __restrict__ q1, const ushort* __restrict__ q2,
    const ushort* __restrict__ q3, const ushort* __restrict__ kmat,
    const ushort* __restrict__ vmat, const float* __restrict__ Z,
    ushort* __restrict__ O)
{
  const int bh = blockIdx.x;
  const int b = bh / Hh, h = bh % Hh;
  const int tid  = threadIdx.x;
  const int lane = tid & 63;
  const int wave = tid >> 6;
  const int g    = lane >> 4;           // 0..3 quad group
  const int trow0 = blockIdx.y * 64 + wave * 16;

  __shared__ ushort Ksh[2][64][64];   // dbuf, gload_lds + XOR swizzle
  __shared__ ushort Vsh[2][64][72];   // dbuf, transposed [d][s]
  __shared__ ushort Psh[64][72];      // P row-major [t][s]; own-wave rows

  const int srow = lane >> 3;
  const int scolb = ((lane & 7) ^ srow) << 4;
  const ushort* Kg = kmat + (size_t)(b*Tt)*Ee + h*Dd;
  const ushort* Vg = vmat + (size_t)(b*Tt)*Ee + h*Dd;

  auto stageK = [&](int buf, int s0) {
#pragma unroll
    for (int rr = 0; rr < 2; rr++) {
      const int rowbase = rr*32 + wave*8;
      gload16((const char*)(Kg + (size_t)(s0 + rowbase + srow)*Ee) + scolb,
              &Ksh[buf][rowbase][0]);
    }
  };

  bf16x8 vstage[2];                    // V in-flight regs (8 VGPR)
  auto vload = [&](int s0) {
#pragma unroll
    for (int u = 0; u < 2; u++) {
      const int c = ((tid >> 6) + 4*u) << 3;
      vstage[u] = *(const bf16x8*)(Vg + (size_t)(s0 + (tid & 63))*Ee + c);
    }
  };
  auto vwrite = [&](int buf) {
#pragma unroll
    for (int u = 0; u < 2; u++) {
      const int c = ((tid >> 6) + 4*u) << 3;
#pragma unroll
      for (int e = 0; e < 8; e++) Vsh[buf][c + e][tid & 63] = (ushort)vstage[u][e];
    }
  };

  const ushort* qs[3] = {q1, q2, q3};
  bf16x8 qf[3][2];   // B-frag: col t = lane&15, k(d) = kk*32 + g*8
#pragma unroll
  for (int j = 0; j < 3; j++)
#pragma unroll
    for (int kk = 0; kk < 2; kk++) {
      const int t = trow0 + (lane & 15);
      const int d = kk*32 + (g << 3);
      qf[j][kk] = *(const bf16x8*)(qs[j] + ((size_t)(b*Tt + t))*Ee + h*Dd + d);
    }

  float cj[3];
#pragma unroll
  for (int j = 0; j < 3; j++) cj[j] = (float)Tt / (3.0f * Z[bh*3 + j]);

  stageK(0, 0);
  vload(0);
  vwrite(0);
  asm volatile("s_waitcnt vmcnt(0)" ::: "memory");
  __syncthreads();

  f32x4 oacc[4] = {};
  const int prow = wave*16 + (lane & 15);

#pragma unroll 1   // MUST stay rolled (spill lesson r5-r10)
  for (int it = 0; it < 16; it++) {
    const int cur = it & 1;
    if (it + 1 < 16) {                 // issue next-tile loads early
      stageK(cur ^ 1, (it + 1) * 64);
      vload((it + 1) * 64);
    }

    // swapped QK^T on cur: sacc rows = s (n*16 + 4g + r), col = t = lane&15
    f32x4 pacc[4] = {};
#pragma unroll
    for (int j = 0; j < 3; j++) {
      f32x4 sacc[4] = {};
#pragma unroll
      for (int kk = 0; kk < 2; kk++) {
        bf16x8 kf[4];   // A-frag: row s = lane&15, k(d) contiguous
#pragma unroll
        for (int n = 0; n < 4; n++)
          kf[n] = *(const bf16x8*)((const char*)&Ksh[cur][n*16 + (lane & 15)][0] +
                    (((g << 4) + kk*64) ^ ((lane & 7) << 4)));
#pragma unroll
        for (int n = 0; n < 4; n++)
          sacc[n] = mfma16(kf[n], qf[j][kk], sacc[n]);
      }
#pragma unroll
      for (int n = 0; n < 4; n++)
#pragma unroll
        for (int r = 0; r < 4; r++)
          pacc[n][r] += cj[j] * exp2x(sacc[n][r]);
    }
    // P write: lane holds P[s: n*16+4g .. +4][t=prow] -> row-major b64 writes
#pragma unroll
    for (int n = 0; n < 4; n++)
      *(uint2*)&Psh[prow][n*16 + (g << 2)] =
          make_uint2(pack2(pacc[n][0], pacc[n][1]), pack2(pacc[n][2], pacc[n][3]));
    // PV: A-frag P (own-wave rows, t = lane&15, k = s contig), B-frag V[d][s]
#pragma unroll
    for (int kk = 0; kk < 2; kk++) {
      const bf16x8 pa = *(const bf16x8*)&Psh[wave*16 + (lane & 15)][kk*32 + (g << 3)];
      bf16x8 vb[4];
#pragma unroll
      for (int n = 0; n < 4; n++)
        vb[n] = *(const bf16x8*)&Vsh[cur][n*16 + (lane & 15)][kk*32 + (g << 3)];
#pragma unroll
      for (int n = 0; n < 4; n++)
        oacc[n] = mfma16(pa, vb[n], oacc[n]);
    }
    if (it + 1 < 16) vwrite(cur ^ 1);  // late transpose-write (T14)
    __syncthreads();                   // one barrier/iter
  }
  // epilogue: C col = d = lane&15, row = t = 4g + r
#pragma unroll
  for (int n = 0; n < 4; n++)
#pragma unroll
    for (int r = 0; r < 4; r++) {
      const int t = trow0 + (g << 2) + r;
      const int d = n*16 + (lane & 15);
      O[((size_t)(b*Tt + t))*Ee + h*Dd + d] = f2b(oacc[n][r]);
    }
}

extern "C" void kernel_launch(void* const* d_in, const int* in_sizes, int n_in,
                              void* d_out, int out_size, void* d_ws, size_t ws_size,
                              hipStream_t stream) {
  const float* X[5];
  for (int i = 0; i < 5; i++) X[i] = (const float*)d_in[i];
  const float* W[6];  const float* bias[6];
  for (int j = 0; j < 6; j++) {
    W[j]    = (const float*)d_in[5 + 2*j];
    bias[j] = (const float*)d_in[6 + 2*j];
  }

  char* ws = (char*)d_ws;
  const size_t segX = (size_t)NTOK * Ee * sizeof(ushort);   // 6.29 MB
  const size_t segW = (size_t)Ee * Ee * sizeof(ushort);     // 1.18 MB
  ushort* Xbf[5];
  for (int i = 0; i < 5; i++) Xbf[i] = (ushort*)(ws + i*segX);
  ushort* Wbf[6];
  for (int j = 0; j < 6; j++) Wbf[j] = (ushort*)(ws + 5*segX + j*segW);
  ushort* Pout[5];
  for (int i = 0; i < 5; i++) Pout[i] = (ushort*)(ws + 5*segX + 6*segW + i*segX);
  ushort* Ob = Xbf[0];   // Xbf dead after proj5; reuse for attention output
  float*  Zp = (float*)(ws + 10*segX + 6*segW);

  CvtArgs ca;
  for (int i = 0; i < 5; i++) ca.seg[i]     = {X[i], Xbf[i], NTOK*Ee/8, 1.0f};
  for (int j = 0; j < 6; j++) ca.seg[5 + j] = {W[j], Wbf[j], Ee*Ee/8,
                                               (j < 3) ? QSCALE : 1.0f};

  ProjPtrs pp;
  for (int i = 0; i < 5; i++) {
    pp.X[i] = Xbf[i]; pp.W[i] = Wbf[i]; pp.b[i] = bias[i]; pp.out[i] = Pout[i];
    pp.bscale[i] = (i < 3) ? QSCALE : 1.0f;
  }

  hipMemsetAsync(Zp, 0, 48*3*sizeof(float), stream);
  convert_kernel<<<dim3(1536, 11), 256, 0, stream>>>(ca);
  proj5_kernel<<<dim3(32, 6, 5), 256, 0, stream>>>(pp);
  attn_pass1<<<dim3(48, 16, 2), 256, 0, stream>>>(Pout[0], Pout[1], Pout[2], Pout[3], Zp);
  attn_pass2<<<dim3(48, 16), 256, 0, stream>>>(Pout[0], Pout[1], Pout[2], Pout[3], Pout[4], Zp, Ob);
  outproj_kernel<<<dim3(32, 6), 256, 0, stream>>>(Ob, Wbf[5], bias[5], (float*)d_out);
}

// Round 13
// 151.594 us; speedup vs baseline: 1.2853x; 1.2853x over previous
//
#include <hip/hip_runtime.h>
#include <hip/hip_bf16.h>

#define Bb 4
#define Tt 1024
#define Ee 768
#define Hh 12
#define Dd 64
#define NTOK (Bb*Tt)   // 4096

// softmax scale 1/sqrt(D)/TEMP folded with log2(e) into Wq/bq so the
// exponential is a bare v_exp_f32 (2^x) on the raw MFMA output.
#define QSCALE 0.18033688f   // 0.125 * log2(e)

typedef __attribute__((ext_vector_type(8))) short bf16x8;  // 8 bf16 in 4 VGPRs
typedef __attribute__((ext_vector_type(4))) float f32x4;   // MFMA accumulator

__device__ __forceinline__ f32x4 mfma16(bf16x8 a, bf16x8 b, f32x4 c) {
  return __builtin_amdgcn_mfma_f32_16x16x32_bf16(a, b, c, 0, 0, 0);
}
__device__ __forceinline__ float exp2x(float x) {
  return __builtin_amdgcn_exp2f(x);
}

// fp32 -> bf16 round-to-nearest-even
__device__ __forceinline__ ushort f2b(float f) {
  uint u = __builtin_bit_cast(uint, f);
  return (ushort)((u + 0x7fffu + ((u >> 16) & 1u)) >> 16);
}
__device__ __forceinline__ uint pack2(float a, float b) {
  return (uint)f2b(a) | ((uint)f2b(b) << 16);
}

// async global->LDS, 16B per lane. LDS dest is wave-uniform base + lane*16.
typedef const __attribute__((address_space(1))) void GV;
typedef __attribute__((address_space(3))) void LV;
__device__ __forceinline__ void gload16(const void* g, void* l) {
  __builtin_amdgcn_global_load_lds((GV*)g, (LV*)l, 16, 0, 0);
}

// ---------------- convert: fp32 -> bf16 (* scale), 8 elems/thread --------
struct CvtSeg { const float* src; ushort* dst; int n8; float scale; };
struct CvtArgs { CvtSeg seg[11]; };

__global__ __launch_bounds__(256) void convert_kernel(CvtArgs a) {
  const CvtSeg s = a.seg[blockIdx.y];
  const int i = blockIdx.x * 256 + threadIdx.x;
  if (i >= s.n8) return;
  const float4 v0 = ((const float4*)s.src)[2*i];
  const float4 v1 = ((const float4*)s.src)[2*i + 1];
  uint4 o;
  o.x = pack2(v0.x * s.scale, v0.y * s.scale);
  o.y = pack2(v0.z * s.scale, v0.w * s.scale);
  o.z = pack2(v1.x * s.scale, v1.y * s.scale);
  o.w = pack2(v1.z * s.scale, v1.w * s.scale);
  ((uint4*)s.dst)[i] = o;
}

// ---------------- bf16 GEMM: C[M,N] = A[M,K] @ W[N,K]^T + bias*bscale ----
// 128x128 tile, BK=64, 4 waves (each a 64x64 quadrant, 4x4 frags).
// Double-buffered LDS with prefetch-before-compute ((256,2): 256-reg cap,
// no spill risk). XOR-swizzle staging (pre-swizzled source + swizzled
// ds_read; involution byte^=(row&7)<<4).
template<bool OUT_BF16>
__device__ __forceinline__ void gemm_bf16(
    const ushort* __restrict__ A, const ushort* __restrict__ Bw,
    const float* __restrict__ bias, const float bscale, void* __restrict__ Cp,
    const int K, const int N)
{
  __shared__ ushort Ash[2][128][64];
  __shared__ ushort Bsh[2][128][64];
  const int tid  = threadIdx.x;
  const int lane = tid & 63;
  const int wave = tid >> 6;
  const int m0 = blockIdx.x * 128;
  const int n0 = blockIdx.y * 128;
  const int wm = (wave >> 1) << 6;
  const int wn = (wave & 1) << 6;
  const int srow = lane >> 3;                       // 0..7 within 8-row group
  const int scol = ((lane & 7) ^ srow) << 3;        // swizzled element offset
  const ushort* Ag = A  + (size_t)(m0 + wave*8 + srow) * K + scol;
  const ushort* Bg = Bw + (size_t)(n0 + wave*8 + srow) * K + scol;

  auto stage = [&](int buf, int k0) {
#pragma unroll
    for (int rr = 0; rr < 4; rr++) {
      gload16(Ag + (size_t)(rr*32) * K + k0, &Ash[buf][rr*32 + wave*8][0]);
      gload16(Bg + (size_t)(rr*32) * K + k0, &Bsh[buf][rr*32 + wave*8][0]);
    }
  };

  stage(0, 0);
  asm volatile("s_waitcnt vmcnt(0)" ::: "memory");
  __syncthreads();

  const int nk = K / 64;
  f32x4 acc[4][4] = {};
  for (int kt = 0; kt < nk; kt++) {
    const int cur = kt & 1;
    if (kt + 1 < nk) stage(cur ^ 1, (kt + 1) * 64);
#pragma unroll
    for (int kk = 0; kk < 2; kk++) {
      const int pcb = (((lane >> 4) << 4) + kk*64) ^ ((lane & 7) << 4);
      bf16x8 af[4], bfv[4];
#pragma unroll
      for (int m = 0; m < 4; m++)
        af[m] = *(const bf16x8*)((const char*)&Ash[cur][wm + m*16 + (lane & 15)][0] + pcb);
#pragma unroll
      for (int n = 0; n < 4; n++)
        bfv[n] = *(const bf16x8*)((const char*)&Bsh[cur][wn + n*16 + (lane & 15)][0] + pcb);
#pragma unroll
      for (int m = 0; m < 4; m++)
#pragma unroll
        for (int n = 0; n < 4; n++)
          acc[m][n] = mfma16(af[m], bfv[n], acc[m][n]);
    }
    __syncthreads();   // drains vmcnt (prefetch) + lgkmcnt, seals buffers
  }
  // C/D layout: col = lane&15, row = (lane>>4)*4 + reg  [m89-verified]
#pragma unroll
  for (int n = 0; n < 4; n++) {
    const int col = n0 + wn + n*16 + (lane & 15);
    const float bv = bias[col] * bscale;
#pragma unroll
    for (int m = 0; m < 4; m++) {
#pragma unroll
      for (int r = 0; r < 4; r++) {
        const int row = m0 + wm + m*16 + ((lane >> 4) << 2) + r;
        const float v = acc[m][n][r] + bv;
        if (OUT_BF16) ((ushort*)Cp)[(size_t)row * N + col] = f2b(v);
        else          ((float*)Cp)[(size_t)row * N + col] = v;
      }
    }
  }
}

struct ProjPtrs {
  const ushort* X[5];
  const ushort* W[5];
  const float* b[5];
  float bscale[5];
  ushort* out[5];
};

__global__ __launch_bounds__(256, 2) void proj5_kernel(ProjPtrs p) {
  const int z = blockIdx.z;
  gemm_bf16<true>(p.X[z], p.W[z], p.b[z], p.bscale[z], p.out[z], Ee, Ee);
}

__global__ __launch_bounds__(256, 2) void outproj_kernel(
    const ushort* __restrict__ A, const ushort* __restrict__ W,
    const float* __restrict__ bias, float* __restrict__ C) {
  gemm_bf16<false>(A, W, bias, 1.0f, C, Ee, Ee);
}

// ---------------- Attention ----------------
// Global-flat softmax: a_j = 2^(St_j)/Z_j * T, Z_j = sum over all (t,s) per
// (b,h). Scores bounded so raw exp2 in fp32 is safe (Q pre-scaled by QSCALE).
//
// CODEGEN/OCCUPANCY LESSONS:
// (r5-r9) statically-known s-loop trip count <= 8 gets FULLY UNROLLED and
// the merged live ranges spill ~1.3 KB/thread. Pin with #pragma unroll 1.
// (r10/r12) occupancy lever is CLOSED for these bodies: >4 waves/EU is
// register-infeasible (r12: (256,6) split the file to 40 arch VGPR and
// spilled 26 MB even with the pin); extra blocks without extra slots just
// add dispatch rounds (r10). Lever that remains: more work per barrier.
// (r11) dbuf+unroll-1 is clean (52 VGPR) and worth ~+6% on pass1; pass2
// dbuf measured a ~4 us LOSS (r11 A/B) -> pass2 stays single-buffer.

// pass1: Z[bh*3+j] = sum 2^s_j. grid (48 bh, 16 strips), 4 waves x 16 rows.
// KVBLK=128: 8 dbuf iterations, 48 MFMA + 96 exp per barrier interval
// (r13: halves barrier-drain stalls vs KVBLK=64).
__global__ __launch_bounds__(256, 3) void attn_pass1(
    const ushort* __restrict__ q1, const ushort* __restrict__ q2,
    const ushort* __restrict__ q3, const ushort* __restrict__ kmat,
    float* __restrict__ Z)
{
  const int bh = blockIdx.x;
  const int b = bh / Hh, h = bh % Hh;
  const int lane = threadIdx.x & 63;
  const int wave = threadIdx.x >> 6;
  const int trow0 = blockIdx.y * 64 + wave * 16;

  __shared__ ushort Ksh[2][128][64];   // dbuf 128-row tiles; XOR-swizzled

  const int srow = lane >> 3;
  const int scolb = ((lane & 7) ^ srow) << 4;       // byte offset in 128B row
  const ushort* Kg = kmat + (size_t)(b*Tt)*Ee + h*Dd;

  auto stageK = [&](int buf, int s0) {
#pragma unroll
    for (int rr = 0; rr < 4; rr++) {
      const int rowbase = rr*32 + wave*8;
      gload16((const char*)(Kg + (size_t)(s0 + rowbase + srow)*Ee) + scolb,
              &Ksh[buf][rowbase][0]);
    }
  };

  const ushort* qs[3] = {q1, q2, q3};
  bf16x8 qf[3][2];
#pragma unroll
  for (int j = 0; j < 3; j++)
#pragma unroll
    for (int kk = 0; kk < 2; kk++) {
      const int t = trow0 + (lane & 15);
      const int d = kk*32 + ((lane >> 4) << 3);
      qf[j][kk] = *(const bf16x8*)(qs[j] + ((size_t)(b*Tt + t))*Ee + h*Dd + d);
    }

  stageK(0, 0);
  asm volatile("s_waitcnt vmcnt(0)" ::: "memory");
  __syncthreads();

  float zacc[3] = {0.f, 0.f, 0.f};
#pragma unroll 1   // MUST stay rolled (spill lesson r5-r10)
  for (int it = 0; it < 8; it++) {
    const int cur = it & 1;
    if (it + 1 < 8) stageK(cur ^ 1, (it + 1) * 128);   // overlaps compute
#pragma unroll
    for (int nh = 0; nh < 2; nh++) {    // two 64-row halves of the 128-tile
      bf16x8 kf[4][2];
#pragma unroll
      for (int n = 0; n < 4; n++)
#pragma unroll
        for (int kk = 0; kk < 2; kk++)
          kf[n][kk] = *(const bf16x8*)((const char*)&Ksh[cur][nh*64 + n*16 + (lane & 15)][0] +
                        ((((lane >> 4) << 4) + kk*64) ^ ((lane & 7) << 4)));
#pragma unroll
      for (int j = 0; j < 3; j++) {
        f32x4 sacc[4] = {};
#pragma unroll
        for (int kk = 0; kk < 2; kk++)
#pragma unroll
          for (int n = 0; n < 4; n++)
            sacc[n] = mfma16(qf[j][kk], kf[n][kk], sacc[n]);
        float s = 0.f;
#pragma unroll
        for (int n = 0; n < 4; n++)
#pragma unroll
          for (int r = 0; r < 4; r++)
            s += exp2x(sacc[n][r]);
        zacc[j] += s;
      }
    }
    __syncthreads();   // one barrier per 128-row tile
  }
#pragma unroll
  for (int j = 0; j < 3; j++) {
    float v = zacc[j];
#pragma unroll
    for (int off = 32; off > 0; off >>= 1) v += __shfl_xor(v, off, 64);
    if (lane == 0) atomicAdd(&Z[bh*3 + j], v);
  }
}

// pass2: O[t,d] = sum_s P[t,s] V[s,d], P = sum_j c_j 2^s_j, c_j = T/(3 Z_j).
// Swapped QK (S^T = mfma(K,Q)) so each lane's 4 C-regs are 4 consecutive s
// for one t -> P write to LDS is 4x b64. Single-buffer staging (r11 A/B:
// pass2 dbuf was a loss). [r8 body verbatim]
__global__ __launch_bounds__(256, 3) void attn_pass2(
    const ushort* __restrict__ q1, const ushort* __restrict__ q2,
    const ushort* __restrict__ q3, const ushort* __restrict__ kmat,
    const ushort* __restrict__ vmat, const float* __restrict__ Z,
    ushort* __restrict__ O)
{
  const int bh = blockIdx.x;
  const int b = bh / Hh, h = bh % Hh;
  const int tid  = threadIdx.x;
  const int lane = tid & 63;
  const int wave = tid >> 6;
  const int g    = lane >> 4;           // 0..3 quad group
  const int trow0 = blockIdx.y * 64 + wave * 16;

  __shared__ ushort Ksh[64][64];      // gload_lds + XOR swizzle
  __shared__ ushort Vsh[64][72];      // transposed [d][s]
  __shared__ ushort Psh[64][72];      // P row-major [t][s]; own-wave rows

  const int srow = lane >> 3;
  const int scolb = ((lane & 7) ^ srow) << 4;
  const ushort* Kg = kmat + (size_t)(b*Tt)*Ee + h*Dd;
  const ushort* Vg = vmat + (size_t)(b*Tt)*Ee + h*Dd;

  const ushort* qs[3] = {q1, q2, q3};
  bf16x8 qf[3][2];   // B-frag: col t = lane&15, k(d) = kk*32 + g*8
#pragma unroll
  for (int j = 0; j < 3; j++)
#pragma unroll
    for (int kk = 0; kk < 2; kk++) {
      const int t = trow0 + (lane & 15);
      const int d = kk*32 + (g << 3);
      qf[j][kk] = *(const bf16x8*)(qs[j] + ((size_t)(b*Tt + t))*Ee + h*Dd + d);
    }

  float cj[3];
#pragma unroll
  for (int j = 0; j < 3; j++) cj[j] = (float)Tt / (3.0f * Z[bh*3 + j]);

  f32x4 oacc[4] = {};
  const int prow = wave*16 + (lane & 15);

  for (int s0 = 0; s0 < Tt; s0 += 64) {
    __syncthreads();
#pragma unroll
    for (int rr = 0; rr < 2; rr++) {
      const int rowbase = rr*32 + wave*8;
      gload16((const char*)(Kg + (size_t)(s0 + rowbase + srow)*Ee) + scolb,
              &Ksh[rowbase][0]);
    }
#pragma unroll
    for (int u = 0; u < 2; u++) {       // V tile, transposed direct write
      const int c = ((tid >> 6) + 4*u) << 3;
      bf16x8 v = *(const bf16x8*)(Vg + (size_t)(s0 + (tid & 63))*Ee + c);
#pragma unroll
      for (int e = 0; e < 8; e++) Vsh[c + e][tid & 63] = (ushort)v[e];
    }
    __syncthreads();

    // swapped QK^T: sacc rows = s (n*16 + 4g + r), col = t = lane&15
    f32x4 pacc[4] = {};
#pragma unroll
    for (int j = 0; j < 3; j++) {
      f32x4 sacc[4] = {};
#pragma unroll
      for (int kk = 0; kk < 2; kk++) {
        bf16x8 kf[4];   // A-frag: row s = lane&15, k(d) contiguous
#pragma unroll
        for (int n = 0; n < 4; n++)
          kf[n] = *(const bf16x8*)((const char*)&Ksh[n*16 + (lane & 15)][0] +
                    (((g << 4) + kk*64) ^ ((lane & 7) << 4)));
#pragma unroll
        for (int n = 0; n < 4; n++)
          sacc[n] = mfma16(kf[n], qf[j][kk], sacc[n]);
      }
#pragma unroll
      for (int n = 0; n < 4; n++)
#pragma unroll
        for (int r = 0; r < 4; r++)
          pacc[n][r] += cj[j] * exp2x(sacc[n][r]);
    }
    // P write: lane holds P[s: n*16+4g .. +4][t=prow] -> row-major b64 writes
#pragma unroll
    for (int n = 0; n < 4; n++)
      *(uint2*)&Psh[prow][n*16 + (g << 2)] =
          make_uint2(pack2(pacc[n][0], pacc[n][1]), pack2(pacc[n][2], pacc[n][3]));
    // PV: A-frag P (own-wave rows, t = lane&15, k = s contig), B-frag V[d][s]
#pragma unroll
    for (int kk = 0; kk < 2; kk++) {
      const bf16x8 pa = *(const bf16x8*)&Psh[wave*16 + (lane & 15)][kk*32 + (g << 3)];
      bf16x8 vb[4];
#pragma unroll
      for (int n = 0; n < 4; n++)
        vb[n] = *(const bf16x8*)&Vsh[n*16 + (lane & 15)][kk*32 + (g << 3)];
#pragma unroll
      for (int n = 0; n < 4; n++)
        oacc[n] = mfma16(pa, vb[n], oacc[n]);
    }
  }
  // epilogue: C col = d = lane&15, row = t = 4g + r
#pragma unroll
  for (int n = 0; n < 4; n++)
#pragma unroll
    for (int r = 0; r < 4; r++) {
      const int t = trow0 + (g << 2) + r;
      const int d = n*16 + (lane & 15);
      O[((size_t)(b*Tt + t))*Ee + h*Dd + d] = f2b(oacc[n][r]);
    }
}

extern "C" void kernel_launch(void* const* d_in, const int* in_sizes, int n_in,
                              void* d_out, int out_size, void* d_ws, size_t ws_size,
                              hipStream_t stream) {
  const float* X[5];
  for (int i = 0; i < 5; i++) X[i] = (const float*)d_in[i];
  const float* W[6];  const float* bias[6];
  for (int j = 0; j < 6; j++) {
    W[j]    = (const float*)d_in[5 + 2*j];
    bias[j] = (const float*)d_in[6 + 2*j];
  }

  char* ws = (char*)d_ws;
  const size_t segX = (size_t)NTOK * Ee * sizeof(ushort);   // 6.29 MB
  const size_t segW = (size_t)Ee * Ee * sizeof(ushort);     // 1.18 MB
  ushort* Xbf[5];
  for (int i = 0; i < 5; i++) Xbf[i] = (ushort*)(ws + i*segX);
  ushort* Wbf[6];
  for (int j = 0; j < 6; j++) Wbf[j] = (ushort*)(ws + 5*segX + j*segW);
  ushort* Pout[5];
  for (int i = 0; i < 5; i++) Pout[i] = (ushort*)(ws + 5*segX + 6*segW + i*segX);
  ushort* Ob = Xbf[0];   // Xbf dead after proj5; reuse for attention output
  float*  Zp = (float*)(ws + 10*segX + 6*segW);

  CvtArgs ca;
  for (int i = 0; i < 5; i++) ca.seg[i]     = {X[i], Xbf[i], NTOK*Ee/8, 1.0f};
  for (int j = 0; j < 6; j++) ca.seg[5 + j] = {W[j], Wbf[j], Ee*Ee/8,
                                               (j < 3) ? QSCALE : 1.0f};

  ProjPtrs pp;
  for (int i = 0; i < 5; i++) {
    pp.X[i] = Xbf[i]; pp.W[i] = Wbf[i]; pp.b[i] = bias[i]; pp.out[i] = Pout[i];
    pp.bscale[i] = (i < 3) ? QSCALE : 1.0f;
  }

  hipMemsetAsync(Zp, 0, 48*3*sizeof(float), stream);
  convert_kernel<<<dim3(1536, 11), 256, 0, stream>>>(ca);
  proj5_kernel<<<dim3(32, 6, 5), 256, 0, stream>>>(pp);
  attn_pass1<<<dim3(48, 16), 256, 0, stream>>>(Pout[0], Pout[1], Pout[2], Pout[3], Zp);
  attn_pass2<<<dim3(48, 16), 256, 0, stream>>>(Pout[0], Pout[1], Pout[2], Pout[3], Pout[4], Zp, Ob);
  outproj_kernel<<<dim3(32, 6), 256, 0, stream>>>(Ob, Wbf[5], bias[5], (float*)d_out);
}